// Round 8
// baseline (303.468 us; speedup 1.0000x reference)
//
#include <hip/hip_runtime.h>
#include <hip/hip_bf16.h>

// Problem constants (B,T,C,H,DH) = (2,2048,768,12,64)
#define Bn 2
#define Tn 2048
#define Cn 768
#define Hn 12
#define Dn 64
#define N3n 2304
#define Mn 4096   // B*T

#define MASKVAL (-30000.f)     // finite sentinel (log2-domain scores are O(+-22))
#define NQI 1536               // 64 q-tiles(32 rows) * 12 heads * 2 batch
#define QSC 0.18033688011112042f   // 0.125 * log2(e) — folded into Q

typedef unsigned short u16;
typedef __attribute__((ext_vector_type(8))) unsigned short ushort8_t;
typedef __attribute__((ext_vector_type(8))) short bf16x8;   // 8 bf16 (4 VGPRs)
typedef __attribute__((ext_vector_type(4))) short bf16x4;   // 4 bf16 (2 VGPRs)
typedef __attribute__((ext_vector_type(4))) float f32x4;

__device__ __forceinline__ float bf2f(u16 u) {
  union { unsigned int i; float f; } v; v.i = ((unsigned int)u) << 16; return v.f;
}
__device__ __forceinline__ u16 f2bf(float f) {
  union { float f; unsigned int i; } v; v.f = f;
  return (u16)((v.i + 0x7fffu + ((v.i >> 16) & 1u)) >> 16);
}
__device__ __forceinline__ float exp2c(float x) {
  // v_exp_f32: D = 2^S0. Clamp arg to [-100, 0] -> result in (0,1]; never inf/NaN.
  return __builtin_amdgcn_exp2f(fmaxf(x, -100.f));
}

__device__ __forceinline__ f32x4 mfma32(bf16x8 a, bf16x8 b, f32x4 c) {
  return __builtin_amdgcn_mfma_f32_16x16x32_bf16(a, b, c, 0, 0, 0);
}
__device__ __forceinline__ f32x4 mfma16(bf16x4 a, bf16x4 b, f32x4 c) {
#if __has_builtin(__builtin_amdgcn_mfma_f32_16x16x16bf16_1k)
  return __builtin_amdgcn_mfma_f32_16x16x16bf16_1k(a, b, c, 0, 0, 0);
#else
  f32x4 d;
  asm volatile("v_mfma_f32_16x16x16_bf16 %0, %1, %2, %3"
               : "=&v"(d) : "v"(a), "v"(b), "v"(c));
  return d;
#endif
}

// ---------------------------------------------------------------------------
// Prep 1: fp32 -> bf16 cast (x); block 0 zeroes the attn work counter.
// ---------------------------------------------------------------------------
__global__ __launch_bounds__(256) void cast_bf16(const float* __restrict__ in,
                                                 u16* __restrict__ out,
                                                 int* __restrict__ counter) {
  if (blockIdx.x == 0 && threadIdx.x == 0) *counter = 0;
  const int i = (blockIdx.x * 256 + threadIdx.x) * 4;
  float4 v = *(const float4*)(in + i);
  ushort4 s;
  s.x = f2bf(v.x); s.y = f2bf(v.y); s.z = f2bf(v.z); s.w = f2bf(v.w);
  *(ushort4*)(out + i) = s;
}

// ---------------------------------------------------------------------------
// Prep 2: transpose-cast. in fp32 [R][Cc] -> out bf16 [Cc][R]. 32x32 LDS tile.
// ---------------------------------------------------------------------------
__global__ __launch_bounds__(256) void transpose_cast(const float* __restrict__ in,
                                                      u16* __restrict__ out,
                                                      int R, int Cc) {
  __shared__ u16 t[32][33];
  const int c0 = blockIdx.x * 32, r0 = blockIdx.y * 32;
  const int tx = threadIdx.x, ty = threadIdx.y;
#pragma unroll
  for (int i = 0; i < 4; i++)
    t[ty * 4 + i][tx] = f2bf(in[(size_t)(r0 + ty * 4 + i) * Cc + c0 + tx]);
  __syncthreads();
#pragma unroll
  for (int i = 0; i < 4; i++)
    out[(size_t)(c0 + ty * 4 + i) * R + r0 + tx] = t[tx][ty * 4 + i];
}

// ---------------------------------------------------------------------------
// MFMA GEMM (verified since R5). 128x128 tile, BK=32, 4 waves.
// EPI 0: Q (pre-scaled by QSC), K [B,H,T,DH]; VT [B,H,DH,T].  EPI 1: fp32 out.
// ---------------------------------------------------------------------------
#define GP 40

template <int EPI>
__global__ __launch_bounds__(256) void mfma_gemm(const u16* __restrict__ A,
                                                 const u16* __restrict__ BT,
                                                 u16* __restrict__ Q,
                                                 u16* __restrict__ Kd,
                                                 u16* __restrict__ VT,
                                                 float* __restrict__ out) {
  __shared__ __align__(16) u16 Ash[128 * GP];
  __shared__ __align__(16) u16 Bsh[128 * GP];
  const int tid = threadIdx.x;
  const int wv = tid >> 6, lane = tid & 63;
  const int lo = lane & 15, quad = lane >> 4;
  const int wm = wv & 1, wn = wv >> 1;
  const int n0 = blockIdx.x * 128;
  const int m0 = blockIdx.y * 128;

  f32x4 acc[4][4];
#pragma unroll
  for (int i = 0; i < 4; i++)
#pragma unroll
    for (int j = 0; j < 4; j++) acc[i][j] = f32x4{0.f, 0.f, 0.f, 0.f};

  for (int k0 = 0; k0 < Cn; k0 += 32) {
    __syncthreads();
#pragma unroll
    for (int it = 0; it < 2; it++) {
      const int c = tid + it * 256;
      const int row = c >> 2, col = (c & 3) << 3;
      *(ushort8_t*)&Ash[row * GP + col] =
          *(const ushort8_t*)(A + (size_t)(m0 + row) * Cn + k0 + col);
      *(ushort8_t*)&Bsh[row * GP + col] =
          *(const ushort8_t*)(BT + (size_t)(n0 + row) * Cn + k0 + col);
    }
    __syncthreads();

    bf16x8 af[4], bfr[4];
#pragma unroll
    for (int t = 0; t < 4; t++) {
      af[t]  = *(const bf16x8*)&Ash[(wm * 64 + t * 16 + lo) * GP + (quad << 3)];
      bfr[t] = *(const bf16x8*)&Bsh[(wn * 64 + t * 16 + lo) * GP + (quad << 3)];
    }
#pragma unroll
    for (int mt = 0; mt < 4; mt++)
#pragma unroll
      for (int nt = 0; nt < 4; nt++)
        acc[mt][nt] = mfma32(af[mt], bfr[nt], acc[mt][nt]);
  }

  if (EPI == 0) {
    const int which = n0 / Cn;
    const int h = ((n0 % Cn) >> 6) + wn;
    const int bb = m0 >> 11;
    const int t_base = (m0 & (Tn - 1)) + wm * 64;
    if (which < 2) {
      const float qs = (which == 0) ? QSC : 1.f;   // fold 0.125*log2e into Q
      u16* dst = ((which == 0) ? Q : Kd) + (size_t)(bb * Hn + h) * Tn * Dn;
#pragma unroll
      for (int mt = 0; mt < 4; mt++)
#pragma unroll
        for (int nt = 0; nt < 4; nt++)
#pragma unroll
          for (int r = 0; r < 4; r++) {
            const int t = t_base + mt * 16 + (quad << 2) + r;
            dst[(size_t)t * Dn + nt * 16 + lo] = f2bf(acc[mt][nt][r] * qs);
          }
    } else {
      u16* dst = VT + (size_t)(bb * Hn + h) * Dn * Tn;
#pragma unroll
      for (int mt = 0; mt < 4; mt++)
#pragma unroll
        for (int nt = 0; nt < 4; nt++) {
          const int t = t_base + mt * 16 + (quad << 2);
          const int d = nt * 16 + lo;
          ushort4 st;
          st.x = f2bf(acc[mt][nt][0]); st.y = f2bf(acc[mt][nt][1]);
          st.z = f2bf(acc[mt][nt][2]); st.w = f2bf(acc[mt][nt][3]);
          *(ushort4*)&dst[(size_t)d * Tn + t] = st;
        }
    }
  } else {
#pragma unroll
    for (int mt = 0; mt < 4; mt++)
#pragma unroll
      for (int nt = 0; nt < 4; nt++)
#pragma unroll
        for (int r = 0; r < 4; r++) {
          const int m = m0 + wm * 64 + mt * 16 + (quad << 2) + r;
          out[(size_t)m * Cn + n0 + wn * 64 + nt * 16 + lo] = acc[mt][nt][r];
        }
  }
}

// ---------------------------------------------------------------------------
// Causal flash attention, wave-autonomous, zero LDS, zero barriers.
// Each WAVE pulls a (32-row q-tile, h, b) item (LPT order) and owns it.
// S^T = K.Q^T via 16x16x32 (C-layout lane: kv=quad*4+r, q=lo) -> P^T stays in
// registers and is the exact B-operand of 16x16x16 -> O^T = V^T.P^T.
// Softmax: per-lane local + 2 shfl_xor (16,32). Q pre-scaled, exp2-domain.
// ---------------------------------------------------------------------------
__global__ __launch_bounds__(256) void attn_kernel(const u16* __restrict__ Q,
                                                   const u16* __restrict__ K,
                                                   const u16* __restrict__ VT,
                                                   u16* __restrict__ O,
                                                   int* __restrict__ counter) {
  const int lane = threadIdx.x & 63;
  const int lo = lane & 15, quad = lane >> 4;

  for (;;) {
    int it0 = 0;
    if (lane == 0) it0 = atomicAdd(counter, 1);
    const int it = __builtin_amdgcn_readfirstlane(it0);
    if (it >= NQI) return;

    const int qt = 63 - it / 24;          // LPT: longest q-tiles first
    const int hb = it % 24;
    const int h = hb % Hn, b = hb / Hn;
    const int q0 = qt * 32;
    const size_t base = (size_t)(b * Hn + h) * Tn * Dn;   // Q/K [.,T,64]
    const size_t vtb  = (size_t)(b * Hn + h) * Dn * Tn;   // VT  [.,64,T]

    // Q B-fragments (B-layout: n=lo, k=quad*8+j), pre-scaled by QSC
    bf16x8 aq[2][2];
#pragma unroll
    for (int g = 0; g < 2; g++) {
      const u16* qp = Q + base + (size_t)(q0 + g * 16 + lo) * Dn + (quad << 3);
      aq[g][0] = *(const bf16x8*)qp;
      aq[g][1] = *(const bf16x8*)(qp + 32);
    }

    f32x4 o[2][4];
#pragma unroll
    for (int g = 0; g < 2; g++)
#pragma unroll
      for (int dt = 0; dt < 4; dt++) o[g][dt] = f32x4{0.f, 0.f, 0.f, 0.f};
    float m_[2] = {MASKVAL, MASKVAL}, l_[2] = {0.f, 0.f};

    for (int j0 = 0; j0 <= q0 + 31; j0 += 64) {
      const bool last = (j0 + 64 > q0 + 31);
      const int mtc = last ? (((q0 + 31 - j0) >> 4) + 1) : 4;   // wave-uniform

      // ---- S^T tiles: lane holds (kv = mt*16+quad*4+r, q = g*16+lo) ----
      f32x4 s_[2][4];
#pragma unroll
      for (int mt = 0; mt < 4; mt++) {
        if (mt >= mtc) continue;
        const u16* kp = K + base + (size_t)(j0 + mt * 16 + lo) * Dn + (quad << 3);
        const bf16x8 kf0 = *(const bf16x8*)kp;
        const bf16x8 kf1 = *(const bf16x8*)(kp + 32);
#pragma unroll
        for (int g = 0; g < 2; g++) {
          f32x4 a = {0.f, 0.f, 0.f, 0.f};
          a = mfma32(kf0, aq[g][0], a);
          a = mfma32(kf1, aq[g][1], a);
          s_[g][mt] = a;
        }
      }

      if (last) {
#pragma unroll
        for (int g = 0; g < 2; g++)
#pragma unroll
          for (int mt = 0; mt < 4; mt++) {
            if (mt >= mtc) continue;
#pragma unroll
            for (int r = 0; r < 4; r++) {
              const int kv = j0 + mt * 16 + (quad << 2) + r;
              if (kv > q0 + g * 16 + lo) s_[g][mt][r] = MASKVAL;
            }
          }
      }

      // ---- online softmax (log2 domain): local + 2 shuffles ----
      float alpha[2];
#pragma unroll
      for (int g = 0; g < 2; g++) {
        float mx = MASKVAL;
#pragma unroll
        for (int mt = 0; mt < 4; mt++) {
          if (mt >= mtc) continue;
#pragma unroll
          for (int r = 0; r < 4; r++) mx = fmaxf(mx, s_[g][mt][r]);
        }
        mx = fmaxf(mx, __shfl_xor(mx, 16));
        mx = fmaxf(mx, __shfl_xor(mx, 32));
        const float mnew = fmaxf(m_[g], mx);
        alpha[g] = exp2c(m_[g] - mnew);
        m_[g] = mnew;
        float sum = 0.f;
#pragma unroll
        for (int mt = 0; mt < 4; mt++) {
          if (mt >= mtc) continue;
#pragma unroll
          for (int r = 0; r < 4; r++) {
            const float p = exp2c(s_[g][mt][r] - mnew);
            s_[g][mt][r] = p;
            sum += p;
          }
        }
        sum += __shfl_xor(sum, 16);
        sum += __shfl_xor(sum, 32);
        l_[g] = l_[g] * alpha[g] + sum;
      }

      // ---- rescale O, pack P^T to bf16 (registers only) ----
#pragma unroll
      for (int g = 0; g < 2; g++)
#pragma unroll
        for (int dt = 0; dt < 4; dt++)
#pragma unroll
          for (int r = 0; r < 4; r++) o[g][dt][r] *= alpha[g];

      bf16x4 pf[2][4];
#pragma unroll
      for (int g = 0; g < 2; g++)
#pragma unroll
        for (int mt = 0; mt < 4; mt++) {
          if (mt >= mtc) continue;
          bf16x4 pk;
          pk[0] = (short)f2bf(s_[g][mt][0]);
          pk[1] = (short)f2bf(s_[g][mt][1]);
          pk[2] = (short)f2bf(s_[g][mt][2]);
          pk[3] = (short)f2bf(s_[g][mt][3]);
          pf[g][mt] = pk;
        }

      // ---- O^T += V^T . P^T  (A: m=d=lo, k=kv=quad*4+j; B = pf direct) ----
#pragma unroll
      for (int mt = 0; mt < 4; mt++) {
        if (mt >= mtc) continue;
#pragma unroll
        for (int dt = 0; dt < 4; dt++) {
          const bf16x4 vf = *(const bf16x4*)(VT + vtb +
              (size_t)(dt * 16 + lo) * Tn + j0 + mt * 16 + (quad << 2));
          o[0][dt] = mfma16(vf, pf[0][mt], o[0][dt]);
          o[1][dt] = mfma16(vf, pf[1][mt], o[1][dt]);
        }
      }
    }

    // ---- epilogue: lane holds (q=g*16+lo, d=dt*16+quad*4+r); b64 stores ----
#pragma unroll
    for (int g = 0; g < 2; g++) {
      const float inv = 1.f / l_[g];
      const int row = q0 + g * 16 + lo;
#pragma unroll
      for (int dt = 0; dt < 4; dt++) {
        ushort4 st;
        st.x = f2bf(o[g][dt][0] * inv); st.y = f2bf(o[g][dt][1] * inv);
        st.z = f2bf(o[g][dt][2] * inv); st.w = f2bf(o[g][dt][3] * inv);
        *(ushort4*)(O + (size_t)(b * Tn + row) * Cn + h * 64 + dt * 16 + (quad << 2)) = st;
      }
    }
  }
}

// ---------------------------------------------------------------------------
extern "C" void kernel_launch(void* const* d_in, const int* in_sizes, int n_in,
                              void* d_out, int out_size, void* d_ws, size_t ws_size,
                              hipStream_t stream) {
  const float* x    = (const float*)d_in[0];   // [B,T,C] fp32
  const float* Wqkv = (const float*)d_in[1];   // [C,3C] fp32
  const float* Wout = (const float*)d_in[2];   // [C,C] fp32
  float* out = (float*)d_out;                  // [B,T,C] fp32

  const size_t per = (size_t)Bn * Hn * Tn * Dn;     // 3,145,728 elems
  u16* xb    = (u16*)d_ws;                          // [4096,768] bf16
  u16* WqkvT = xb + (size_t)Mn * Cn;                // [2304,768] bf16
  u16* WoutT = WqkvT + (size_t)N3n * Cn;            // [768,768]  bf16
  u16* Qb    = WoutT + (size_t)Cn * Cn;             // [B,H,T,DH] bf16 (pre-scaled)
  u16* Kb    = Qb + per;                            // [B,H,T,DH] bf16
  u16* VTb   = Kb + per;                            // [B,H,DH,T] bf16
  u16* attn  = VTb + per;                           // [B,T,C]    bf16
  int* counter = (int*)(attn + (size_t)Mn * Cn);    // 4 B
  // total ws use: ~36.2 MB + 4 B (< 50.3 MB available)

  cast_bf16<<<(Mn * Cn) / 1024, 256, 0, stream>>>(x, xb, counter);
  transpose_cast<<<dim3(N3n / 32, Cn / 32), dim3(32, 8), 0, stream>>>(Wqkv, WqkvT, Cn, N3n);
  transpose_cast<<<dim3(Cn / 32, Cn / 32), dim3(32, 8), 0, stream>>>(Wout, WoutT, Cn, Cn);

  mfma_gemm<0><<<dim3(N3n / 128, Mn / 128), 256, 0, stream>>>(xb, WqkvT, Qb, Kb, VTb, nullptr);
  attn_kernel<<<dim3(512), 256, 0, stream>>>(Qb, Kb, VTb, attn, counter);
  mfma_gemm<1><<<dim3(Cn / 128, Mn / 128), 256, 0, stream>>>(attn, WoutT, nullptr, nullptr, nullptr, out);
}

// Round 9
// 224.559 us; speedup vs baseline: 1.3514x; 1.3514x over previous
//
#include <hip/hip_runtime.h>
#include <hip/hip_bf16.h>

// Problem constants (B,T,C,H,DH) = (2,2048,768,12,64)
#define Bn 2
#define Tn 2048
#define Cn 768
#define Hn 12
#define Dn 64
#define N3n 2304
#define Mn 4096   // B*T

#define MASKVAL (-30000.f)     // finite sentinel (log2-domain scores are O(+-22))
#define NITEMS 384             // 16 q-blocks(128 rows) * 12 heads * 2 batch
#define QSC 0.18033688011112042f   // 0.125 * log2(e) — folded into Q

typedef unsigned short u16;
typedef __attribute__((ext_vector_type(8))) unsigned short ushort8_t;
typedef __attribute__((ext_vector_type(8))) short bf16x8;   // 8 bf16 (4 VGPRs)
typedef __attribute__((ext_vector_type(4))) short bf16x4;   // 4 bf16 (2 VGPRs)
typedef __attribute__((ext_vector_type(4))) float f32x4;

__device__ __forceinline__ float bf2f(u16 u) {
  union { unsigned int i; float f; } v; v.i = ((unsigned int)u) << 16; return v.f;
}
__device__ __forceinline__ u16 f2bf(float f) {
  union { float f; unsigned int i; } v; v.f = f;
  return (u16)((v.i + 0x7fffu + ((v.i >> 16) & 1u)) >> 16);
}
__device__ __forceinline__ float exp2c(float x) {
  return __builtin_amdgcn_exp2f(fmaxf(x, -100.f));   // 2^x, arg in [-100,0]
}

__device__ __forceinline__ f32x4 mfma32(bf16x8 a, bf16x8 b, f32x4 c) {
  return __builtin_amdgcn_mfma_f32_16x16x32_bf16(a, b, c, 0, 0, 0);
}
__device__ __forceinline__ f32x4 mfma16(bf16x4 a, bf16x4 b, f32x4 c) {
#if __has_builtin(__builtin_amdgcn_mfma_f32_16x16x16bf16_1k)
  return __builtin_amdgcn_mfma_f32_16x16x16bf16_1k(a, b, c, 0, 0, 0);
#else
  f32x4 d;
  asm volatile("v_mfma_f32_16x16x16_bf16 %0, %1, %2, %3"
               : "=&v"(d) : "v"(a), "v"(b), "v"(c));
  return d;
#endif
}

// ---------------------------------------------------------------------------
// Prep 1: fp32 -> bf16 cast (x); block 0 zeroes the attn work counter.
// ---------------------------------------------------------------------------
__global__ __launch_bounds__(256) void cast_bf16(const float* __restrict__ in,
                                                 u16* __restrict__ out,
                                                 int* __restrict__ counter) {
  if (blockIdx.x == 0 && threadIdx.x == 0) *counter = 0;
  const int i = (blockIdx.x * 256 + threadIdx.x) * 4;
  float4 v = *(const float4*)(in + i);
  ushort4 s;
  s.x = f2bf(v.x); s.y = f2bf(v.y); s.z = f2bf(v.z); s.w = f2bf(v.w);
  *(ushort4*)(out + i) = s;
}

// ---------------------------------------------------------------------------
// Prep 2: transpose-cast. in fp32 [R][Cc] -> out bf16 [Cc][R]. 32x32 LDS tile.
// ---------------------------------------------------------------------------
__global__ __launch_bounds__(256) void transpose_cast(const float* __restrict__ in,
                                                      u16* __restrict__ out,
                                                      int R, int Cc) {
  __shared__ u16 t[32][33];
  const int c0 = blockIdx.x * 32, r0 = blockIdx.y * 32;
  const int tx = threadIdx.x, ty = threadIdx.y;
#pragma unroll
  for (int i = 0; i < 4; i++)
    t[ty * 4 + i][tx] = f2bf(in[(size_t)(r0 + ty * 4 + i) * Cc + c0 + tx]);
  __syncthreads();
#pragma unroll
  for (int i = 0; i < 4; i++)
    out[(size_t)(c0 + ty * 4 + i) * R + r0 + tx] = t[tx][ty * 4 + i];
}

// ---------------------------------------------------------------------------
// MFMA GEMM (verified since R5). 128x128 tile, BK=32, 4 waves.
// EPI 0: Q (pre-scaled by QSC), K [B,H,T,DH]; VT [B,H,DH,T].  EPI 1: fp32 out.
// ---------------------------------------------------------------------------
#define GP 40

template <int EPI>
__global__ __launch_bounds__(256) void mfma_gemm(const u16* __restrict__ A,
                                                 const u16* __restrict__ BT,
                                                 u16* __restrict__ Q,
                                                 u16* __restrict__ Kd,
                                                 u16* __restrict__ VT,
                                                 float* __restrict__ out) {
  __shared__ __align__(16) u16 Ash[128 * GP];
  __shared__ __align__(16) u16 Bsh[128 * GP];
  const int tid = threadIdx.x;
  const int wv = tid >> 6, lane = tid & 63;
  const int lo = lane & 15, quad = lane >> 4;
  const int wm = wv & 1, wn = wv >> 1;
  const int n0 = blockIdx.x * 128;
  const int m0 = blockIdx.y * 128;

  f32x4 acc[4][4];
#pragma unroll
  for (int i = 0; i < 4; i++)
#pragma unroll
    for (int j = 0; j < 4; j++) acc[i][j] = f32x4{0.f, 0.f, 0.f, 0.f};

  for (int k0 = 0; k0 < Cn; k0 += 32) {
    __syncthreads();
#pragma unroll
    for (int it = 0; it < 2; it++) {
      const int c = tid + it * 256;
      const int row = c >> 2, col = (c & 3) << 3;
      *(ushort8_t*)&Ash[row * GP + col] =
          *(const ushort8_t*)(A + (size_t)(m0 + row) * Cn + k0 + col);
      *(ushort8_t*)&Bsh[row * GP + col] =
          *(const ushort8_t*)(BT + (size_t)(n0 + row) * Cn + k0 + col);
    }
    __syncthreads();

    bf16x8 af[4], bfr[4];
#pragma unroll
    for (int t = 0; t < 4; t++) {
      af[t]  = *(const bf16x8*)&Ash[(wm * 64 + t * 16 + lo) * GP + (quad << 3)];
      bfr[t] = *(const bf16x8*)&Bsh[(wn * 64 + t * 16 + lo) * GP + (quad << 3)];
    }
#pragma unroll
    for (int mt = 0; mt < 4; mt++)
#pragma unroll
      for (int nt = 0; nt < 4; nt++)
        acc[mt][nt] = mfma32(af[mt], bfr[nt], acc[mt][nt]);
  }

  if (EPI == 0) {
    const int which = n0 / Cn;
    const int h = ((n0 % Cn) >> 6) + wn;
    const int bb = m0 >> 11;
    const int t_base = (m0 & (Tn - 1)) + wm * 64;
    if (which < 2) {
      const float qs = (which == 0) ? QSC : 1.f;   // fold 0.125*log2e into Q
      u16* dst = ((which == 0) ? Q : Kd) + (size_t)(bb * Hn + h) * Tn * Dn;
#pragma unroll
      for (int mt = 0; mt < 4; mt++)
#pragma unroll
        for (int nt = 0; nt < 4; nt++)
#pragma unroll
          for (int r = 0; r < 4; r++) {
            const int t = t_base + mt * 16 + (quad << 2) + r;
            dst[(size_t)t * Dn + nt * 16 + lo] = f2bf(acc[mt][nt][r] * qs);
          }
    } else {
      u16* dst = VT + (size_t)(bb * Hn + h) * Dn * Tn;
#pragma unroll
      for (int mt = 0; mt < 4; mt++)
#pragma unroll
        for (int nt = 0; nt < 4; nt++) {
          const int t = t_base + mt * 16 + (quad << 2);
          const int d = nt * 16 + lo;
          ushort4 st;
          st.x = f2bf(acc[mt][nt][0]); st.y = f2bf(acc[mt][nt][1]);
          st.z = f2bf(acc[mt][nt][2]); st.w = f2bf(acc[mt][nt][3]);
          *(ushort4*)&dst[(size_t)d * Tn + t] = st;
        }
    }
  } else {
#pragma unroll
    for (int mt = 0; mt < 4; mt++)
#pragma unroll
      for (int nt = 0; nt < 4; nt++)
#pragma unroll
        for (int r = 0; r < 4; r++) {
          const int m = m0 + wm * 64 + mt * 16 + (quad << 2) + r;
          out[(size_t)m * Cn + n0 + wn * 64 + nt * 16 + lo] = acc[mt][nt][r];
        }
  }
}

// ---------------------------------------------------------------------------
// Causal flash attention: LDS-staged K/V^T + register-resident S^T/P^T.
// Block = 4 waves, 128 q-rows (32/wave), same (h,b); LPT work queue (384 items).
// Per j-tile(64 kv): block stages K[64x64] and V^T[64x64] into LDS (pitch 72),
// wave computes S^T = K.Q^T (K A-frags: 8 ds_read_b128), softmax in registers
// (2 shfl), P^T stays in registers (= mfma16 B-operand), O^T += V^T.P^T
// (V A-frags: 16 ds_read_b64, shared across both g).
// ---------------------------------------------------------------------------
#define KP 72   // LDS row pitch in u16 (144 B: 16B-aligned)

__global__ __launch_bounds__(256) void attn_kernel(const u16* __restrict__ Q,
                                                   const u16* __restrict__ K,
                                                   const u16* __restrict__ VT,
                                                   u16* __restrict__ O,
                                                   int* __restrict__ counter) {
  __shared__ __align__(16) u16 Ks[64 * KP];   // K-tile  [kv][d]
  __shared__ __align__(16) u16 Vt[64 * KP];   // V-tile  [d][kv]
  __shared__ int s_item;

  const int tid = threadIdx.x;
  const int wv = tid >> 6, lane = tid & 63;
  const int lo = lane & 15, quad = lane >> 4;

  for (;;) {
    __syncthreads();                 // protect s_item + LDS from prev item
    if (tid == 0) s_item = atomicAdd(counter, 1);
    __syncthreads();
    const int it = s_item;
    if (it >= NITEMS) return;        // uniform exit

    const int q0 = (15 - it / 24) * 128;   // LPT: longest q-blocks first
    const int hb = it % 24;
    const int h = hb % Hn, b = hb / Hn;
    const int wq0 = q0 + wv * 32;          // this wave's 32 q-rows
    const size_t base = (size_t)(b * Hn + h) * Tn * Dn;   // Q/K [.,T,64]
    const size_t vtb  = (size_t)(b * Hn + h) * Dn * Tn;   // VT  [.,64,T]

    // Q B-fragments (n=lo, k=quad*8+j), pre-scaled by QSC
    bf16x8 aq[2][2];
#pragma unroll
    for (int g = 0; g < 2; g++) {
      const u16* qp = Q + base + (size_t)(wq0 + g * 16 + lo) * Dn + (quad << 3);
      aq[g][0] = *(const bf16x8*)qp;
      aq[g][1] = *(const bf16x8*)(qp + 32);
    }

    f32x4 o[2][4];
#pragma unroll
    for (int g = 0; g < 2; g++)
#pragma unroll
      for (int dt = 0; dt < 4; dt++) o[g][dt] = f32x4{0.f, 0.f, 0.f, 0.f};
    float m_[2] = {MASKVAL, MASKVAL}, l_[2] = {0.f, 0.f};

    for (int j0 = 0; j0 <= q0 + 127; j0 += 64) {
      __syncthreads();               // LDS safe to overwrite
      // stage K rows [j0..j0+63][0..63] and VT rows [0..63][j0..j0+63]
      for (int c = tid; c < 512; c += 256) {
        const int r = c >> 3, cc = (c & 7) << 3;
        *(ushort8_t*)(&Ks[r * KP + cc]) =
            *(const ushort8_t*)(K + base + (size_t)(j0 + r) * Dn + cc);
        *(ushort8_t*)(&Vt[r * KP + cc]) =
            *(const ushort8_t*)(VT + vtb + (size_t)r * Tn + j0 + cc);
      }
      __syncthreads();               // staging complete

      if (j0 > wq0 + 31) continue;   // wave past causal range: barriers only

      const bool diag = (j0 + 63 > wq0);
      const int mtc = diag ? (((wq0 + 31 - j0) >> 4) + 1) : 4;  // wave-uniform
      const int mtc4 = (mtc > 4) ? 4 : mtc;

      // ---- S^T: lane holds (kv = mt*16+quad*4+r, q = g*16+lo) ----
      f32x4 s_[2][4];
#pragma unroll
      for (int mt = 0; mt < 4; mt++) {
        if (mt >= mtc4) continue;
        const bf16x8 kf0 = *(const bf16x8*)&Ks[(mt * 16 + lo) * KP + (quad << 3)];
        const bf16x8 kf1 = *(const bf16x8*)&Ks[(mt * 16 + lo) * KP + 32 + (quad << 3)];
#pragma unroll
        for (int g = 0; g < 2; g++) {
          f32x4 a = {0.f, 0.f, 0.f, 0.f};
          a = mfma32(kf0, aq[g][0], a);
          a = mfma32(kf1, aq[g][1], a);
          s_[g][mt] = a;
        }
      }

      if (diag) {
#pragma unroll
        for (int g = 0; g < 2; g++)
#pragma unroll
          for (int mt = 0; mt < 4; mt++) {
            if (mt >= mtc4) continue;
#pragma unroll
            for (int r = 0; r < 4; r++) {
              const int kv = j0 + mt * 16 + (quad << 2) + r;
              if (kv > wq0 + g * 16 + lo) s_[g][mt][r] = MASKVAL;
            }
          }
      }

      // ---- online softmax (log2 domain): local + 2 shuffles per g ----
      float alpha[2];
#pragma unroll
      for (int g = 0; g < 2; g++) {
        float mx = MASKVAL;
#pragma unroll
        for (int mt = 0; mt < 4; mt++) {
          if (mt >= mtc4) continue;
#pragma unroll
          for (int r = 0; r < 4; r++) mx = fmaxf(mx, s_[g][mt][r]);
        }
        mx = fmaxf(mx, __shfl_xor(mx, 16));
        mx = fmaxf(mx, __shfl_xor(mx, 32));
        const float mnew = fmaxf(m_[g], mx);
        alpha[g] = exp2c(m_[g] - mnew);
        m_[g] = mnew;
        float sum = 0.f;
#pragma unroll
        for (int mt = 0; mt < 4; mt++) {
          if (mt >= mtc4) continue;
#pragma unroll
          for (int r = 0; r < 4; r++) {
            const float p = exp2c(s_[g][mt][r] - mnew);
            s_[g][mt][r] = p;
            sum += p;
          }
        }
        sum += __shfl_xor(sum, 16);
        sum += __shfl_xor(sum, 32);
        l_[g] = l_[g] * alpha[g] + sum;
      }

      // ---- rescale O, pack P^T (registers only; exact mfma16 B-layout) ----
#pragma unroll
      for (int g = 0; g < 2; g++)
#pragma unroll
        for (int dt = 0; dt < 4; dt++)
#pragma unroll
          for (int r = 0; r < 4; r++) o[g][dt][r] *= alpha[g];

      bf16x4 pf[2][4];
#pragma unroll
      for (int g = 0; g < 2; g++)
#pragma unroll
        for (int mt = 0; mt < 4; mt++) {
          if (mt >= mtc4) continue;
          bf16x4 pk;
          pk[0] = (short)f2bf(s_[g][mt][0]);
          pk[1] = (short)f2bf(s_[g][mt][1]);
          pk[2] = (short)f2bf(s_[g][mt][2]);
          pk[3] = (short)f2bf(s_[g][mt][3]);
          pf[g][mt] = pk;
        }

      // ---- O^T += V^T . P^T (V A-frags from LDS, shared across g) ----
#pragma unroll
      for (int mt = 0; mt < 4; mt++) {
        if (mt >= mtc4) continue;
#pragma unroll
        for (int dt = 0; dt < 4; dt++) {
          const bf16x4 vf = *(const bf16x4*)&Vt[(dt * 16 + lo) * KP +
                                                mt * 16 + (quad << 2)];
          o[0][dt] = mfma16(vf, pf[0][mt], o[0][dt]);
          o[1][dt] = mfma16(vf, pf[1][mt], o[1][dt]);
        }
      }
    }

    // ---- epilogue: lane holds (q=g*16+lo, d=dt*16+quad*4+r) ----
#pragma unroll
    for (int g = 0; g < 2; g++) {
      const float inv = 1.f / l_[g];
      const int row = wq0 + g * 16 + lo;
#pragma unroll
      for (int dt = 0; dt < 4; dt++) {
        ushort4 st;
        st.x = f2bf(o[g][dt][0] * inv); st.y = f2bf(o[g][dt][1] * inv);
        st.z = f2bf(o[g][dt][2] * inv); st.w = f2bf(o[g][dt][3] * inv);
        *(ushort4*)(O + (size_t)(b * Tn + row) * Cn + h * 64 + dt * 16 + (quad << 2)) = st;
      }
    }
  }
}

// ---------------------------------------------------------------------------
extern "C" void kernel_launch(void* const* d_in, const int* in_sizes, int n_in,
                              void* d_out, int out_size, void* d_ws, size_t ws_size,
                              hipStream_t stream) {
  const float* x    = (const float*)d_in[0];   // [B,T,C] fp32
  const float* Wqkv = (const float*)d_in[1];   // [C,3C] fp32
  const float* Wout = (const float*)d_in[2];   // [C,C] fp32
  float* out = (float*)d_out;                  // [B,T,C] fp32

  const size_t per = (size_t)Bn * Hn * Tn * Dn;     // 3,145,728 elems
  u16* xb    = (u16*)d_ws;                          // [4096,768] bf16
  u16* WqkvT = xb + (size_t)Mn * Cn;                // [2304,768] bf16
  u16* WoutT = WqkvT + (size_t)N3n * Cn;            // [768,768]  bf16
  u16* Qb    = WoutT + (size_t)Cn * Cn;             // [B,H,T,DH] bf16 (pre-scaled)
  u16* Kb    = Qb + per;                            // [B,H,T,DH] bf16
  u16* VTb   = Kb + per;                            // [B,H,DH,T] bf16
  u16* attn  = VTb + per;                           // [B,T,C]    bf16
  int* counter = (int*)(attn + (size_t)Mn * Cn);    // 4 B
  // total ws use: ~36.2 MB + 4 B (< 50.3 MB available)

  cast_bf16<<<(Mn * Cn) / 1024, 256, 0, stream>>>(x, xb, counter);
  transpose_cast<<<dim3(N3n / 32, Cn / 32), dim3(32, 8), 0, stream>>>(Wqkv, WqkvT, Cn, N3n);
  transpose_cast<<<dim3(Cn / 32, Cn / 32), dim3(32, 8), 0, stream>>>(Wout, WoutT, Cn, Cn);

  mfma_gemm<0><<<dim3(N3n / 128, Mn / 128), 256, 0, stream>>>(xb, WqkvT, Qb, Kb, VTb, nullptr);
  attn_kernel<<<dim3(512), 256, 0, stream>>>(Qb, Kb, VTb, attn, counter);
  mfma_gemm<1><<<dim3(Cn / 128, Mn / 128), 256, 0, stream>>>(attn, WoutT, nullptr, nullptr, nullptr, out);
}